// Round 7
// baseline (122.536 us; speedup 1.0000x reference)
//
#include <hip/hip_runtime.h>
#include <hip/hip_bf16.h>
#include <cstddef>

#define N_ROWS 8192
#define M_ROWS 8192
#define D_IN   64
#define H_DIM  32
#define T_OUT  8
#define FDIM   48            // 32 features + qv/1 + 1/ck + 14 zero pad

#define NSPLIT   16          // j-splits (blockIdx.y)
#define JSLICE   (M_ROWS / NSPLIT)   // 512 cols per block
#define JTILE    32
#define NTILES   (JSLICE / JTILE)    // 16 j-tiles per block
#define LOG2E    1.4426950408889634f
#define NHALF_SC (-0.72134752044448169f)   // -0.5*log2(e)

typedef _Float16 half8  __attribute__((ext_vector_type(8)));
typedef _Float16 half4v __attribute__((ext_vector_type(4)));
typedef __fp16   fp16x2 __attribute__((ext_vector_type(2)));
typedef float    f32x16 __attribute__((ext_vector_type(16)));

__device__ __forceinline__ half8 ld_h8(const _Float16* p) {
    return *(const half8*)p;
}

// ---------------------------------------------------------------------------
// Kernel 1: features, column-split (R6 structure, 48-wide output).
// Rows 0..N-1 = MLP(X) scaled by log2e; rows N.. = MLP(Y) unscaled.
// dim32 = X? qv : 1 ; dim33 = X? 1 : ck ; dims 34-47 = 0. (norms folded
// into the QK dot so pair epilogue needs no norm loads/adds)
// ---------------------------------------------------------------------------
__global__ __launch_bounds__(256) void feat_kernel(
    const float* __restrict__ X, const float* __restrict__ Y,
    const float* __restrict__ W1, const float* __restrict__ b1,
    const float* __restrict__ W2, const float* __restrict__ b2,
    const float* __restrict__ W3, const float* __restrict__ b3,
    _Float16* __restrict__ fh, _Float16* __restrict__ fl)
{
    __shared__ float xs [32 * 65];
    __shared__ float w1l[64 * 36];
    __shared__ float w2l[32 * 36];
    __shared__ float w3l[32 * 36];
    __shared__ float h1t[32 * 33];
    __shared__ float h2t[32 * 33];
    __shared__ float psums[8 * 32];
    __shared__ float bl[96];

    const int tid = threadIdx.x;
    const int rowbase = blockIdx.x * 32;           // 512 blocks
    const bool isX = rowbase < N_ROWS;
    const float* src = isX ? (X + (size_t)rowbase * D_IN)
                           : (Y + (size_t)(rowbase - N_ROWS) * D_IN);

    {
        const float4* g4 = (const float4*)src;
        int i0 = tid * 2;
        float4 v0 = g4[i0], v1 = g4[i0 + 1];
        int f0 = tid * 8;
        int r = f0 >> 6, c = f0 & 63;
        float* dst = xs + r * 65 + c;
        dst[0] = v0.x; dst[1] = v0.y; dst[2] = v0.z; dst[3] = v0.w;
        dst[4] = v1.x; dst[5] = v1.y; dst[6] = v1.z; dst[7] = v1.w;
    }
    {
        const float4* g4 = (const float4*)W1;
        int i0 = tid * 2;
        float4 v0 = g4[i0], v1 = g4[i0 + 1];
        int f0 = tid * 8;
        int r = f0 >> 5, c = f0 & 31;
        float* dst = w1l + r * 36 + c;
        ((float4*)dst)[0] = v0; ((float4*)dst)[1] = v1;
    }
    {
        int f0 = tid * 4;
        int r = f0 >> 5, c = f0 & 31;
        *(float4*)(w2l + r * 36 + c) = ((const float4*)W2)[tid];
        *(float4*)(w3l + r * 36 + c) = ((const float4*)W3)[tid];
    }
    if (tid < 32) { bl[tid] = b1[tid]; bl[32 + tid] = b2[tid]; bl[64 + tid] = b3[tid]; }
    __syncthreads();

    const int r  = tid & 31;
    const int c0 = (tid >> 5) * 4;

    float4 a1 = *(const float4*)(bl + c0);
    #pragma unroll
    for (int k = 0; k < 64; ++k) {
        float xv = xs[r * 65 + k];
        float4 w = *(const float4*)(w1l + k * 36 + c0);
        a1.x = fmaf(xv, w.x, a1.x);
        a1.y = fmaf(xv, w.y, a1.y);
        a1.z = fmaf(xv, w.z, a1.z);
        a1.w = fmaf(xv, w.w, a1.w);
    }
    h1t[(c0 + 0) * 33 + r] = fmaxf(a1.x, 0.f);
    h1t[(c0 + 1) * 33 + r] = fmaxf(a1.y, 0.f);
    h1t[(c0 + 2) * 33 + r] = fmaxf(a1.z, 0.f);
    h1t[(c0 + 3) * 33 + r] = fmaxf(a1.w, 0.f);
    __syncthreads();

    float4 a2 = *(const float4*)(bl + 32 + c0);
    #pragma unroll
    for (int k = 0; k < 32; ++k) {
        float xv = h1t[k * 33 + r];
        float4 w = *(const float4*)(w2l + k * 36 + c0);
        a2.x = fmaf(xv, w.x, a2.x);
        a2.y = fmaf(xv, w.y, a2.y);
        a2.z = fmaf(xv, w.z, a2.z);
        a2.w = fmaf(xv, w.w, a2.w);
    }
    h2t[(c0 + 0) * 33 + r] = fmaxf(a2.x, 0.f);
    h2t[(c0 + 1) * 33 + r] = fmaxf(a2.y, 0.f);
    h2t[(c0 + 2) * 33 + r] = fmaxf(a2.z, 0.f);
    h2t[(c0 + 3) * 33 + r] = fmaxf(a2.w, 0.f);
    __syncthreads();

    float4 a3 = *(const float4*)(bl + 64 + c0);
    #pragma unroll
    for (int k = 0; k < 32; ++k) {
        float xv = h2t[k * 33 + r];
        float4 w = *(const float4*)(w3l + k * 36 + c0);
        a3.x = fmaf(xv, w.x, a3.x);
        a3.y = fmaf(xv, w.y, a3.y);
        a3.z = fmaf(xv, w.z, a3.z);
        a3.w = fmaf(xv, w.w, a3.w);
    }
    float v0 = fmaxf(a3.x, 0.f), v1 = fmaxf(a3.y, 0.f);
    float v2 = fmaxf(a3.z, 0.f), v3 = fmaxf(a3.w, 0.f);

    psums[(tid >> 5) * 32 + r] = v0 * v0 + v1 * v1 + v2 * v2 + v3 * v3;

    const float scale = isX ? LOG2E : 1.0f;
    union { _Float16 h[4]; uint2 u; } hh, ll;
    float sv0 = v0 * scale, sv1 = v1 * scale, sv2 = v2 * scale, sv3 = v3 * scale;
    hh.h[0] = (_Float16)sv0; hh.h[1] = (_Float16)sv1;
    hh.h[2] = (_Float16)sv2; hh.h[3] = (_Float16)sv3;
    ll.h[0] = (_Float16)(sv0 - (float)hh.h[0]);
    ll.h[1] = (_Float16)(sv1 - (float)hh.h[1]);
    ll.h[2] = (_Float16)(sv2 - (float)hh.h[2]);
    ll.h[3] = (_Float16)(sv3 - (float)hh.h[3]);
    const size_t fo = (size_t)(rowbase + r) * FDIM + c0;
    *(uint2*)(fh + fo) = hh.u;
    *(uint2*)(fl + fo) = ll.u;

    __syncthreads();
    if (tid < 32) {
        float nrm = 0.f;
        #pragma unroll
        for (int g = 0; g < 8; ++g) nrm += psums[g * 32 + tid];
        float qn = NHALF_SC * nrm;
        float d32 = isX ? qn : 1.0f;
        float d33 = isX ? 1.0f : qn;
        union { _Float16 h[16]; uint4 q[2]; } eh, el;
        #pragma unroll
        for (int i = 0; i < 16; ++i) { eh.h[i] = (_Float16)0.f; el.h[i] = (_Float16)0.f; }
        _Float16 h32 = (_Float16)d32, h33 = (_Float16)d33;
        eh.h[0] = h32; eh.h[1] = h33;
        el.h[0] = (_Float16)(d32 - (float)h32);
        el.h[1] = (_Float16)(d33 - (float)h33);
        const size_t eo = (size_t)(rowbase + tid) * FDIM + 32;
        *(uint4*)(fh + eo) = eh.q[0]; *(uint4*)(fh + eo + 8) = eh.q[1];
        *(uint4*)(fl + eo) = el.q[0]; *(uint4*)(fl + eo + 8) = el.q[1];
    }
}

// ---------------------------------------------------------------------------
// Kernel 2: Y_target in PV B-fragment order for mfma_32x32x8_f16.
// For tile jt, group g, lane l (t = l&31, h = l>>5):
//   yf[((jt*4+g)*64 + l)*4 + i'] = Ytt[j = jt*32 + 8g + 4h + i'][t]
// where Ytt[j][t] = Yt[j][t] for t<8, 1 for t==8, 0 for t>8. hi/lo planes.
// ---------------------------------------------------------------------------
__global__ __launch_bounds__(256) void ytt_kernel(
    const float* __restrict__ Yt,
    _Float16* __restrict__ yfh, _Float16* __restrict__ yfl)
{
    const int idx = blockIdx.x * 256 + threadIdx.x;   // 0..65535
    const int lane = idx & 63;
    const int jtg  = idx >> 6;
    const int g    = jtg & 3;
    const int jt   = jtg >> 2;
    const int t    = lane & 31;
    const int h    = lane >> 5;
    const int j    = jt * 32 + g * 8 + h * 4;
    union { _Float16 hh[4]; uint2 u; } H, L;
    #pragma unroll
    for (int i = 0; i < 4; ++i) {
        float v = (t < T_OUT) ? Yt[(size_t)(j + i) * T_OUT + t]
                              : (t == 8 ? 1.0f : 0.0f);
        _Float16 hi = (_Float16)v;
        H.hh[i] = hi;
        L.hh[i] = (_Float16)(v - (float)hi);
    }
    *(uint2*)(yfh + (size_t)idx * 4) = H.u;
    *(uint2*)(yfl + (size_t)idx * 4) = L.u;
}

// ---------------------------------------------------------------------------
// Kernel 3: fused pair kernel, register-only P handoff.
// S^T = Kfeat·Qfeat^T via 9x mfma_32x32x16_f16 (hi/lo x 3 K-chunks of 48).
// C layout: lane holds Q-row i = lane&31, K-rows j = (r&3)+8(r>>2)+4h —
// reg-group g holds j = 8g+4h+{0..3}, which IS the A-layout of
// mfma_32x32x8_f16 (k = 4(lane>>5)+j'). exp2 epilogue packs P hi/lo
// directly into PV A-frags; Ytt B-frags come fragment-ordered from ws.
// No LDS, no barriers, no cross-lane traffic.
// ---------------------------------------------------------------------------
__global__ __launch_bounds__(256, 4) void pair_kernel(
    const _Float16* __restrict__ fh, const _Float16* __restrict__ fl,
    const _Float16* __restrict__ yfh, const _Float16* __restrict__ yfl,
    float* __restrict__ pout, float* __restrict__ psum)
{
    const int tid  = threadIdx.x;
    const int wave = tid >> 6;
    const int lane = tid & 63;
    const int n    = lane & 31;
    const int h    = lane >> 5;

    const int rowbase = blockIdx.x * 128 + wave * 32;   // Q rows
    const int s       = blockIdx.y;
    const int jstart  = s * JSLICE;

    // Q-side B fragments (persist across j-loop): chunks c at k=16c+8h+j'
    const _Float16* qb  = fh + (size_t)(rowbase + n) * FDIM + h * 8;
    const _Float16* qbl = fl + (size_t)(rowbase + n) * FDIM + h * 8;
    half8 qh0 = ld_h8(qb);        half8 qh1 = ld_h8(qb + 16);
    half8 qh2 = ld_h8(qb + 32);
    half8 ql0 = ld_h8(qbl);       half8 ql1 = ld_h8(qbl + 16);
    half8 ql2 = ld_h8(qbl + 32);

    f32x16 o = {};   // O accumulator: col t = lane&31, row i per reg

    for (int jt = 0; jt < NTILES; ++jt) {
        const int jbase = jstart + jt * JTILE;

        // K-side A fragments
        const _Float16* ka  = fh + (size_t)(N_ROWS + jbase + n) * FDIM + h * 8;
        const _Float16* kal = fl + (size_t)(N_ROWS + jbase + n) * FDIM + h * 8;
        half8 kh0 = ld_h8(ka);        half8 kh1 = ld_h8(ka + 16);
        half8 kh2 = ld_h8(ka + 32);
        half8 kl0 = ld_h8(kal);       half8 kl1 = ld_h8(kal + 16);
        half8 kl2 = ld_h8(kal + 32);

        // S^T = K·Q^T with norms folded in dims 32/33 (acc = log2e*(-sq/2))
        f32x16 acc = {};
        acc = __builtin_amdgcn_mfma_f32_32x32x16_f16(kh0, qh0, acc, 0, 0, 0);
        acc = __builtin_amdgcn_mfma_f32_32x32x16_f16(kh1, qh1, acc, 0, 0, 0);
        acc = __builtin_amdgcn_mfma_f32_32x32x16_f16(kh2, qh2, acc, 0, 0, 0);
        acc = __builtin_amdgcn_mfma_f32_32x32x16_f16(kh0, ql0, acc, 0, 0, 0);
        acc = __builtin_amdgcn_mfma_f32_32x32x16_f16(kh1, ql1, acc, 0, 0, 0);
        acc = __builtin_amdgcn_mfma_f32_32x32x16_f16(kh2, ql2, acc, 0, 0, 0);
        acc = __builtin_amdgcn_mfma_f32_32x32x16_f16(kl0, qh0, acc, 0, 0, 0);
        acc = __builtin_amdgcn_mfma_f32_32x32x16_f16(kl1, qh1, acc, 0, 0, 0);
        acc = __builtin_amdgcn_mfma_f32_32x32x16_f16(kl2, qh2, acc, 0, 0, 0);

        // Epilogue: w = 2^min(acc,0); pack hi/lo straight into PV A-frags.
        half4v phi[4], plo[4];
        #pragma unroll
        for (int g = 0; g < 4; ++g) {
            float w0 = __builtin_amdgcn_exp2f(fminf(acc[4*g+0], 0.f));
            float w1 = __builtin_amdgcn_exp2f(fminf(acc[4*g+1], 0.f));
            float w2 = __builtin_amdgcn_exp2f(fminf(acc[4*g+2], 0.f));
            float w3 = __builtin_amdgcn_exp2f(fminf(acc[4*g+3], 0.f));
            fp16x2 p01 = __builtin_amdgcn_cvt_pkrtz(w0, w1);
            fp16x2 p23 = __builtin_amdgcn_cvt_pkrtz(w2, w3);
            fp16x2 l01 = __builtin_amdgcn_cvt_pkrtz(w0 - (float)p01[0],
                                                    w1 - (float)p01[1]);
            fp16x2 l23 = __builtin_amdgcn_cvt_pkrtz(w2 - (float)p23[0],
                                                    w3 - (float)p23[1]);
            union { unsigned int u[2]; half4v v; } ph, pl;
            ph.u[0] = __builtin_bit_cast(unsigned int, p01);
            ph.u[1] = __builtin_bit_cast(unsigned int, p23);
            pl.u[0] = __builtin_bit_cast(unsigned int, l01);
            pl.u[1] = __builtin_bit_cast(unsigned int, l23);
            phi[g] = ph.v; plo[g] = pl.v;
        }

        // PV: O += P·Ytt via 32x32x8, fragment-ordered B from ws.
        const size_t yb = ((size_t)((s * NTILES + jt) * 4) * 64 + lane) * 4;
        #pragma unroll
        for (int g = 0; g < 4; ++g) {
            half4v bh = *(const half4v*)(yfh + yb + (size_t)g * 256);
            half4v bl = *(const half4v*)(yfl + yb + (size_t)g * 256);
            o = __builtin_amdgcn_mfma_f32_32x32x8f16(phi[g], bh, o, 0, 0, 0);
            o = __builtin_amdgcn_mfma_f32_32x32x8f16(plo[g], bh, o, 0, 0, 0);
            o = __builtin_amdgcn_mfma_f32_32x32x8f16(phi[g], bl, o, 0, 0, 0);
        }
    }

    // Writeout: col t = lane&31; rows i = (r&3)+8*(r>>2)+4h.
    const int t = n;
    if (t <= 8) {
        #pragma unroll
        for (int r = 0; r < 16; ++r) {
            int i = (r & 3) + 8 * (r >> 2) + 4 * h;
            int row = rowbase + i;
            float v = o[r];
            if (t < 8)
                pout[((size_t)s * N_ROWS + row) * T_OUT + t] = v;
            else
                psum[(size_t)s * N_ROWS + row] = v;
        }
    }
}

// ---------------------------------------------------------------------------
// Kernel 4: reduce partials across NSPLIT j-slices and normalize.
// ---------------------------------------------------------------------------
__global__ __launch_bounds__(256) void reduce_kernel(
    const float* __restrict__ pout, const float* __restrict__ psum,
    float* __restrict__ out)
{
    const int id = blockIdx.x * 256 + threadIdx.x;   // 0..65535
    const int i = id >> 3;
    float sv = 0.f, sw = 0.f;
    #pragma unroll
    for (int s = 0; s < NSPLIT; ++s) {
        sv += pout[(size_t)s * N_ROWS * T_OUT + id];
        sw += psum[(size_t)s * N_ROWS + i];
    }
    out[id] = sv / sw;
}

// ---------------------------------------------------------------------------
extern "C" void kernel_launch(void* const* d_in, const int* in_sizes, int n_in,
                              void* d_out, int out_size, void* d_ws, size_t ws_size,
                              hipStream_t stream)
{
    const float* X  = (const float*)d_in[0];
    const float* Y  = (const float*)d_in[1];
    const float* Yt = (const float*)d_in[2];
    const float* W1 = (const float*)d_in[3];
    const float* b1 = (const float*)d_in[4];
    const float* W2 = (const float*)d_in[5];
    const float* b2 = (const float*)d_in[6];
    const float* W3 = (const float*)d_in[7];
    const float* b3 = (const float*)d_in[8];
    float* out = (float*)d_out;

    char* ws = (char*)d_ws;
    const size_t n_feat = (size_t)(N_ROWS + M_ROWS) * FDIM;            // 786432
    _Float16* fh  = (_Float16*)ws;   ws += n_feat * 2;                 // 1.5 MB
    _Float16* fl  = (_Float16*)ws;   ws += n_feat * 2;                 // 1.5 MB
    const size_t n_yf = (size_t)(M_ROWS / JTILE) * 4 * 64 * 4;         // 262144
    _Float16* yfh = (_Float16*)ws;   ws += n_yf * 2;                   // 512 KB
    _Float16* yfl = (_Float16*)ws;   ws += n_yf * 2;                   // 512 KB
    float*    pout = (float*)ws;     ws += (size_t)NSPLIT * N_ROWS * T_OUT * 4; // 4 MB
    float*    psum = (float*)ws;                                       // 512 KB

    feat_kernel<<<(N_ROWS + M_ROWS) / 32, 256, 0, stream>>>(
        X, Y, W1, b1, W2, b2, W3, b3, fh, fl);
    ytt_kernel<<<(M_ROWS / JTILE) * 4 * 64 / 256, 256, 0, stream>>>(Yt, yfh, yfl);

    dim3 grid2(N_ROWS / 128, NSPLIT);
    pair_kernel<<<grid2, 256, 0, stream>>>(fh, fl, yfh, yfl, pout, psum);

    reduce_kernel<<<(N_ROWS * T_OUT) / 256, 256, 0, stream>>>(pout, psum, out);
}